// Round 5
// baseline (300.219 us; speedup 1.0000x reference)
//
#include <hip/hip_runtime.h>

// GrCNet attention layer — CSR gather formulation.
//   u[n] = W1 x[n], v[n] = W2 x[n]   (a = [W1 | W2], [64,128] row-major)
//   su[n] = u[n].a2, sv[n] = v[n].a2
//   edge e: g = 0.5*(G[s,t]+G[d,t]); ee = exp(-lrelu(g*(su[s]+sv[d]))); w = ee*g
//   CSR-by-src stores packed int4 (d, w, ee, 0)
//   h[n] = elu( ((Σw)·u[n] + Σ w·v[d]) / Σee )
//
// Round 5: de-confound round 4's regression —
//  - scan: single-block kernel (no cross-block spin chain, no 3-launch chain)
//  - rowsum: back to register accumulation of ee in aggregate (no float atomics)
//  - CSR: one int4 record per edge (single 16B transaction each way)
//  - kept: x4-unrolled gather, count zeroing fused into node_transform

#define LRELU_ALPHA 0.2f

__global__ __launch_bounds__(256) void node_transform_kernel(
    const float* __restrict__ x, const float* __restrict__ a,
    const float* __restrict__ a2,
    float* __restrict__ u, float* __restrict__ v,
    float* __restrict__ su, float* __restrict__ sv,
    int* __restrict__ count, int N)
{
    __shared__ float a_lds[64][129];
    for (int idx = threadIdx.x; idx < 64 * 128; idx += 256)
        a_lds[idx >> 7][idx & 127] = a[idx];
    __syncthreads();

    const int wave = threadIdx.x >> 6;
    const int lane = threadIdx.x & 63;
    const int n = blockIdx.x * 4 + wave;
    if (n >= N) return;

    if (lane == 0) count[n] = 0;

    const float a2v = a2[lane];
    const float* xr = x + (size_t)n * 64;
    float uo = 0.f, vo = 0.f;
#pragma unroll 8
    for (int i = 0; i < 64; ++i) {
        const float xi = xr[i];
        uo += xi * a_lds[lane][i];
        vo += xi * a_lds[lane][64 + i];
    }
    u[(size_t)n * 64 + lane] = uo;
    v[(size_t)n * 64 + lane] = vo;

    float sup = uo * a2v, svp = vo * a2v;
#pragma unroll
    for (int m = 1; m < 64; m <<= 1) {
        sup += __shfl_xor(sup, m, 64);
        svp += __shfl_xor(svp, m, 64);
    }
    if (lane == 0) { su[n] = sup; sv[n] = svp; }
}

__global__ __launch_bounds__(256) void hist_kernel(
    const int* __restrict__ edge, int* __restrict__ count, int E)
{
    const int i = blockIdx.x * 256 + threadIdx.x;
    if (i < E) atomicAdd(&count[edge[i]], 1);
}

// single-block exclusive scan: 1024 threads, ~49 items each (N=50k).
// No cross-block dependency; ~5 us; one launch.
__global__ __launch_bounds__(1024) void scan_single_kernel(
    const int* __restrict__ count, int* __restrict__ base,
    int* __restrict__ cursor, int N)
{
    __shared__ int lds[1024];
    const int t = threadIdx.x;
    const int items = (N + 1023) >> 10;
    const int i0 = t * items;

    int s = 0;
    for (int k = 0; k < items; ++k) {
        const int idx = i0 + k;
        s += (idx < N) ? count[idx] : 0;
    }
    lds[t] = s;
    __syncthreads();
    for (int off = 1; off < 1024; off <<= 1) {
        const int xv = (t >= off) ? lds[t - off] : 0;
        __syncthreads();
        lds[t] += xv;
        __syncthreads();
    }
    int run = (t == 0) ? 0 : lds[t - 1];
    for (int k = 0; k < items; ++k) {
        const int idx = i0 + k;
        if (idx < N) {
            base[idx] = run;
            cursor[idx] = run;
            run += count[idx];
        }
    }
}

// one THREAD per edge: scalar score + packed CSR placement (cursor atomic only)
__global__ __launch_bounds__(256) void edge_place_kernel(
    const int* __restrict__ edge, const int* __restrict__ etype,
    const float* __restrict__ G, int R,
    const float* __restrict__ su, const float* __restrict__ sv,
    int* __restrict__ cursor, int4* __restrict__ csr,
    int E, int N)
{
    const int e = blockIdx.x * 256 + threadIdx.x;
    if (e >= E) return;
    const int s = edge[e];
    const int d = edge[(size_t)E + e];
    const int t = etype[e];
    if ((unsigned)s >= (unsigned)N || (unsigned)d >= (unsigned)N) return;

    const float g   = 0.5f * (G[s * R + t] + G[d * R + t]);
    const float raw = g * (su[s] + sv[d]);
    const float lr  = raw > 0.f ? raw : LRELU_ALPHA * raw;
    const float ee  = __expf(-lr);

    const int pos = atomicAdd(&cursor[s], 1);
    csr[pos] = make_int4(d, __float_as_int(ee * g), __float_as_int(ee), 0);
}

// one WAVE per node: register accumulation, x4-unrolled gather, fused finalize
__global__ __launch_bounds__(256) void aggregate_kernel(
    const int* __restrict__ base, const int4* __restrict__ csr,
    const float* __restrict__ u, const float* __restrict__ v,
    float* __restrict__ out, int N, int E)
{
    const int wave = threadIdx.x >> 6;
    const int lane = threadIdx.x & 63;
    const int n = blockIdx.x * 4 + wave;
    if (n >= N) return;

    const int rs = base[n];
    const int re = (n + 1 < N) ? base[n + 1] : E;

    float val = 0.f, sumw_p = 0.f, sumee_p = 0.f;

    for (int i = rs; i < re; i += 64) {
        const int m = min(64, re - i);
        int dl = 0; float wl = 0.f, eel = 0.f;
        if (lane < m) {
            const int4 p = csr[i + lane];
            dl  = p.x;
            wl  = __int_as_float(p.y);
            eel = __int_as_float(p.z);
        }
        sumw_p  += wl;
        sumee_p += eel;
        int j = 0;
        for (; j + 4 <= m; j += 4) {
            const int   d0 = __shfl(dl, j,     64);
            const int   d1 = __shfl(dl, j + 1, 64);
            const int   d2 = __shfl(dl, j + 2, 64);
            const int   d3 = __shfl(dl, j + 3, 64);
            const float w0 = __shfl(wl, j,     64);
            const float w1 = __shfl(wl, j + 1, 64);
            const float w2 = __shfl(wl, j + 2, 64);
            const float w3 = __shfl(wl, j + 3, 64);
            const float v0 = v[d0 * 64 + lane];
            const float v1 = v[d1 * 64 + lane];
            const float v2 = v[d2 * 64 + lane];
            const float v3 = v[d3 * 64 + lane];
            val += w0 * v0;
            val += w1 * v1;
            val += w2 * v2;
            val += w3 * v3;
        }
        for (; j < m; ++j) {
            const int   dj = __shfl(dl, j, 64);
            const float wj = __shfl(wl, j, 64);
            val += wj * v[dj * 64 + lane];
        }
    }

    float sumw = sumw_p, sumee = sumee_p;
#pragma unroll
    for (int m2 = 1; m2 < 64; m2 <<= 1) {
        sumw  += __shfl_xor(sumw,  m2, 64);
        sumee += __shfl_xor(sumee, m2, 64);
    }

    val += sumw * u[n * 64 + lane];
    const float r = (sumee == 0.f) ? 1e-12f : sumee;
    const float h = val / r;
    out[n * 64 + lane] = (h > 0.f) ? h : expm1f(h);
}

extern "C" void kernel_launch(void* const* d_in, const int* in_sizes, int n_in,
                              void* d_out, int out_size, void* d_ws, size_t ws_size,
                              hipStream_t stream)
{
    const float* x     = (const float*)d_in[0];
    const int*   edge  = (const int*)d_in[1];
    // d_in[2] = edge_embed: unused by the reference computation
    const int*   etype = (const int*)d_in[3];
    const float* G     = (const float*)d_in[4];
    const float* a     = (const float*)d_in[5];
    const float* a2    = (const float*)d_in[6];

    const int N = in_sizes[0] / 64;
    const int E = in_sizes[1] / 2;
    const int R = in_sizes[4] / N;

    float* out = (float*)d_out;

    // workspace layout (~39 MB):
    // u[N*64] | v[N*64] | su[N] | sv[N] | count[N] | base[N] | cursor[N] | csr[E] (int4)
    float* u      = (float*)d_ws;
    float* v      = u + (size_t)N * 64;
    float* su     = v + (size_t)N * 64;
    float* sv     = su + N;
    int*   count  = (int*)(sv + N);
    int*   base   = count + N;
    int*   cursor = base + N;
    int*   tail   = cursor + N;
    int4*  csr    = (int4*)((((uintptr_t)tail) + 15) & ~(uintptr_t)15);

    node_transform_kernel<<<dim3((N + 3) / 4), dim3(256), 0, stream>>>(
        x, a, a2, u, v, su, sv, count, N);
    hist_kernel<<<dim3((E + 255) / 256), dim3(256), 0, stream>>>(edge, count, E);
    scan_single_kernel<<<dim3(1), dim3(1024), 0, stream>>>(count, base, cursor, N);
    edge_place_kernel<<<dim3((E + 255) / 256), dim3(256), 0, stream>>>(
        edge, etype, G, R, su, sv, cursor, csr, E, N);
    aggregate_kernel<<<dim3((N + 3) / 4), dim3(256), 0, stream>>>(
        base, csr, u, v, out, N, E);
}

// Round 6
// 187.942 us; speedup vs baseline: 1.5974x; 1.5974x over previous
//
#include <hip/hip_runtime.h>

// GrCNet attention layer — CSR gather formulation.
//   u[n] = W1 x[n], v[n] = W2 x[n]   (a = [W1 | W2], [64,128] row-major)
//   su[n] = u[n].a2, sv[n] = v[n].a2
//   edge e: g = 0.5*(G[s,t]+G[d,t]); ee = exp(-lrelu(g*(su[s]+sv[d]))); w = ee*g
//   CSR-by-src stores packed int4 (d, w, ee, 0)
//   h[n] = elu( ((Σw)·u[n] + Σ w·v[d]) / Σee )
//
// Round 6: single-block scan was 125 us (1 CU, latency-bound) — revert to the
// proven 3-kernel parallel scan from rounds 2/3 (~15 us total). Keep round 5's
// int4 CSR, register-ee rowsum, x4-unrolled aggregate.

#define LRELU_ALPHA 0.2f
#define SCAN_BLOCK 256
#define SCAN_ITEMS 8
#define SCAN_TILE (SCAN_BLOCK * SCAN_ITEMS)  // 2048

__global__ __launch_bounds__(256) void node_transform_kernel(
    const float* __restrict__ x, const float* __restrict__ a,
    const float* __restrict__ a2,
    float* __restrict__ u, float* __restrict__ v,
    float* __restrict__ su, float* __restrict__ sv,
    int* __restrict__ count, int N)
{
    __shared__ float a_lds[64][129];
    for (int idx = threadIdx.x; idx < 64 * 128; idx += 256)
        a_lds[idx >> 7][idx & 127] = a[idx];
    __syncthreads();

    const int wave = threadIdx.x >> 6;
    const int lane = threadIdx.x & 63;
    const int n = blockIdx.x * 4 + wave;
    if (n >= N) return;

    if (lane == 0) count[n] = 0;

    const float a2v = a2[lane];
    const float* xr = x + (size_t)n * 64;
    float uo = 0.f, vo = 0.f;
#pragma unroll 8
    for (int i = 0; i < 64; ++i) {
        const float xi = xr[i];
        uo += xi * a_lds[lane][i];
        vo += xi * a_lds[lane][64 + i];
    }
    u[(size_t)n * 64 + lane] = uo;
    v[(size_t)n * 64 + lane] = vo;

    float sup = uo * a2v, svp = vo * a2v;
#pragma unroll
    for (int m = 1; m < 64; m <<= 1) {
        sup += __shfl_xor(sup, m, 64);
        svp += __shfl_xor(svp, m, 64);
    }
    if (lane == 0) { su[n] = sup; sv[n] = svp; }
}

__global__ __launch_bounds__(256) void hist_kernel(
    const int* __restrict__ edge, int* __restrict__ count, int E)
{
    const int i = blockIdx.x * 256 + threadIdx.x;
    if (i < E) atomicAdd(&count[edge[i]], 1);
}

__global__ __launch_bounds__(256) void scan_blocks_kernel(
    const int* __restrict__ count, int* __restrict__ base,
    int* __restrict__ blocksums, int N)
{
    __shared__ int lds[SCAN_BLOCK];
    const int b = blockIdx.x, t = threadIdx.x;
    const int idx0 = b * SCAN_TILE + t * SCAN_ITEMS;
    int vals[SCAN_ITEMS];
    int s = 0;
#pragma unroll
    for (int k = 0; k < SCAN_ITEMS; ++k) {
        const int idx = idx0 + k;
        const int c = (idx < N) ? count[idx] : 0;
        vals[k] = s; s += c;
    }
    lds[t] = s;
    __syncthreads();
    for (int off = 1; off < SCAN_BLOCK; off <<= 1) {
        const int xv = (t >= off) ? lds[t - off] : 0;
        __syncthreads();
        lds[t] += xv;
        __syncthreads();
    }
    const int excl = (t == 0) ? 0 : lds[t - 1];
#pragma unroll
    for (int k = 0; k < SCAN_ITEMS; ++k) {
        const int idx = idx0 + k;
        if (idx < N) base[idx] = excl + vals[k];
    }
    if (t == SCAN_BLOCK - 1) blocksums[b] = lds[t];
}

__global__ void scan_tops_kernel(int* __restrict__ blocksums, int nb)
{
    if (threadIdx.x == 0 && blockIdx.x == 0) {
        int s = 0;
        for (int i = 0; i < nb; ++i) { const int c = blocksums[i]; blocksums[i] = s; s += c; }
    }
}

__global__ __launch_bounds__(256) void scan_add_kernel(
    int* __restrict__ base, const int* __restrict__ blocksums,
    int* __restrict__ cursor, int N)
{
    const int i = blockIdx.x * 256 + threadIdx.x;
    if (i < N) {
        const int bv = base[i] + blocksums[i / SCAN_TILE];
        base[i] = bv;
        cursor[i] = bv;
    }
}

// one THREAD per edge: scalar score + packed CSR placement (cursor atomic only)
__global__ __launch_bounds__(256) void edge_place_kernel(
    const int* __restrict__ edge, const int* __restrict__ etype,
    const float* __restrict__ G, int R,
    const float* __restrict__ su, const float* __restrict__ sv,
    int* __restrict__ cursor, int4* __restrict__ csr,
    int E, int N)
{
    const int e = blockIdx.x * 256 + threadIdx.x;
    if (e >= E) return;
    const int s = edge[e];
    const int d = edge[(size_t)E + e];
    const int t = etype[e];
    if ((unsigned)s >= (unsigned)N || (unsigned)d >= (unsigned)N) return;

    const float g   = 0.5f * (G[s * R + t] + G[d * R + t]);
    const float raw = g * (su[s] + sv[d]);
    const float lr  = raw > 0.f ? raw : LRELU_ALPHA * raw;
    const float ee  = __expf(-lr);

    const int pos = atomicAdd(&cursor[s], 1);
    csr[pos] = make_int4(d, __float_as_int(ee * g), __float_as_int(ee), 0);
}

// one WAVE per node: register accumulation, x4-unrolled gather, fused finalize
__global__ __launch_bounds__(256) void aggregate_kernel(
    const int* __restrict__ base, const int4* __restrict__ csr,
    const float* __restrict__ u, const float* __restrict__ v,
    float* __restrict__ out, int N, int E)
{
    const int wave = threadIdx.x >> 6;
    const int lane = threadIdx.x & 63;
    const int n = blockIdx.x * 4 + wave;
    if (n >= N) return;

    const int rs = base[n];
    const int re = (n + 1 < N) ? base[n + 1] : E;

    float val = 0.f, sumw_p = 0.f, sumee_p = 0.f;

    for (int i = rs; i < re; i += 64) {
        const int m = min(64, re - i);
        int dl = 0; float wl = 0.f, eel = 0.f;
        if (lane < m) {
            const int4 p = csr[i + lane];
            dl  = p.x;
            wl  = __int_as_float(p.y);
            eel = __int_as_float(p.z);
        }
        sumw_p  += wl;
        sumee_p += eel;
        int j = 0;
        for (; j + 4 <= m; j += 4) {
            const int   d0 = __shfl(dl, j,     64);
            const int   d1 = __shfl(dl, j + 1, 64);
            const int   d2 = __shfl(dl, j + 2, 64);
            const int   d3 = __shfl(dl, j + 3, 64);
            const float w0 = __shfl(wl, j,     64);
            const float w1 = __shfl(wl, j + 1, 64);
            const float w2 = __shfl(wl, j + 2, 64);
            const float w3 = __shfl(wl, j + 3, 64);
            const float v0 = v[d0 * 64 + lane];
            const float v1 = v[d1 * 64 + lane];
            const float v2 = v[d2 * 64 + lane];
            const float v3 = v[d3 * 64 + lane];
            val += w0 * v0;
            val += w1 * v1;
            val += w2 * v2;
            val += w3 * v3;
        }
        for (; j < m; ++j) {
            const int   dj = __shfl(dl, j, 64);
            const float wj = __shfl(wl, j, 64);
            val += wj * v[dj * 64 + lane];
        }
    }

    float sumw = sumw_p, sumee = sumee_p;
#pragma unroll
    for (int m2 = 1; m2 < 64; m2 <<= 1) {
        sumw  += __shfl_xor(sumw,  m2, 64);
        sumee += __shfl_xor(sumee, m2, 64);
    }

    val += sumw * u[n * 64 + lane];
    const float r = (sumee == 0.f) ? 1e-12f : sumee;
    const float h = val / r;
    out[n * 64 + lane] = (h > 0.f) ? h : expm1f(h);
}

extern "C" void kernel_launch(void* const* d_in, const int* in_sizes, int n_in,
                              void* d_out, int out_size, void* d_ws, size_t ws_size,
                              hipStream_t stream)
{
    const float* x     = (const float*)d_in[0];
    const int*   edge  = (const int*)d_in[1];
    // d_in[2] = edge_embed: unused by the reference computation
    const int*   etype = (const int*)d_in[3];
    const float* G     = (const float*)d_in[4];
    const float* a     = (const float*)d_in[5];
    const float* a2    = (const float*)d_in[6];

    const int N = in_sizes[0] / 64;
    const int E = in_sizes[1] / 2;
    const int R = in_sizes[4] / N;

    float* out = (float*)d_out;

    // workspace layout (~39 MB):
    // u[N*64] | v[N*64] | su[N] | sv[N] | count[N] | base[N] | cursor[N] |
    // blocksums[nsb] | csr[E] (int4)
    float* u      = (float*)d_ws;
    float* v      = u + (size_t)N * 64;
    float* su     = v + (size_t)N * 64;
    float* sv     = su + N;
    int*   count  = (int*)(sv + N);
    int*   base   = count + N;
    int*   cursor = base + N;
    const int nsb = (N + SCAN_TILE - 1) / SCAN_TILE;
    int*   blocksums = cursor + N;
    int*   tail   = blocksums + ((nsb + 63) & ~63);
    int4*  csr    = (int4*)((((uintptr_t)tail) + 15) & ~(uintptr_t)15);

    node_transform_kernel<<<dim3((N + 3) / 4), dim3(256), 0, stream>>>(
        x, a, a2, u, v, su, sv, count, N);
    hist_kernel<<<dim3((E + 255) / 256), dim3(256), 0, stream>>>(edge, count, E);
    scan_blocks_kernel<<<dim3(nsb), dim3(SCAN_BLOCK), 0, stream>>>(count, base, blocksums, N);
    scan_tops_kernel<<<dim3(1), dim3(64), 0, stream>>>(blocksums, nsb);
    scan_add_kernel<<<dim3((N + 255) / 256), dim3(256), 0, stream>>>(base, blocksums, cursor, N);
    edge_place_kernel<<<dim3((E + 255) / 256), dim3(256), 0, stream>>>(
        edge, etype, G, R, su, sv, cursor, csr, E, N);
    aggregate_kernel<<<dim3((N + 3) / 4), dim3(256), 0, stream>>>(
        base, csr, u, v, out, N, E);
}

// Round 7
// 180.076 us; speedup vs baseline: 1.6672x; 1.0437x over previous
//
#include <hip/hip_runtime.h>

// GrCNet attention layer — CSR gather formulation.
//   u[n] = W1 x[n], v[n] = W2 x[n]   (a = [W1 | W2], [64,128] row-major)
//   su[n] = u[n].a2, sv[n] = v[n].a2
//   edge e: g = 0.5*(G[s,t]+G[d,t]); ee = exp(-lrelu(g*(su[s]+sv[d]))); w = ee*g
//   CSR-by-src stores packed int4 (d, w, ee, 0)
//   h[n] = elu( ((Σw)·u[n] + Σ w·v[d]) / Σee )
//
// Round 7: (1) hist's atomicAdd return value IS the edge's rank within its
// source — store rank[e], so edge_place does pos = base[s]+rank[e] with no
// atomic (removes 800k random atomic RMWs + the cursor array entirely).
// (2) aggregate inner gather loop unrolled x8 (then x4, then tail).

#define LRELU_ALPHA 0.2f
#define SCAN_BLOCK 256
#define SCAN_ITEMS 8
#define SCAN_TILE (SCAN_BLOCK * SCAN_ITEMS)  // 2048

__global__ __launch_bounds__(256) void node_transform_kernel(
    const float* __restrict__ x, const float* __restrict__ a,
    const float* __restrict__ a2,
    float* __restrict__ u, float* __restrict__ v,
    float* __restrict__ su, float* __restrict__ sv,
    int* __restrict__ count, int N)
{
    __shared__ float a_lds[64][129];
    for (int idx = threadIdx.x; idx < 64 * 128; idx += 256)
        a_lds[idx >> 7][idx & 127] = a[idx];
    __syncthreads();

    const int wave = threadIdx.x >> 6;
    const int lane = threadIdx.x & 63;
    const int n = blockIdx.x * 4 + wave;
    if (n >= N) return;

    if (lane == 0) count[n] = 0;

    const float a2v = a2[lane];
    const float* xr = x + (size_t)n * 64;
    float uo = 0.f, vo = 0.f;
#pragma unroll 8
    for (int i = 0; i < 64; ++i) {
        const float xi = xr[i];
        uo += xi * a_lds[lane][i];
        vo += xi * a_lds[lane][64 + i];
    }
    u[(size_t)n * 64 + lane] = uo;
    v[(size_t)n * 64 + lane] = vo;

    float sup = uo * a2v, svp = vo * a2v;
#pragma unroll
    for (int m = 1; m < 64; m <<= 1) {
        sup += __shfl_xor(sup, m, 64);
        svp += __shfl_xor(svp, m, 64);
    }
    if (lane == 0) { su[n] = sup; sv[n] = svp; }
}

// histogram + free rank capture (atomicAdd's return value)
__global__ __launch_bounds__(256) void hist_kernel(
    const int* __restrict__ edge, int* __restrict__ count,
    int* __restrict__ rank, int E)
{
    const int i = blockIdx.x * 256 + threadIdx.x;
    if (i < E) rank[i] = atomicAdd(&count[edge[i]], 1);
}

__global__ __launch_bounds__(256) void scan_blocks_kernel(
    const int* __restrict__ count, int* __restrict__ base,
    int* __restrict__ blocksums, int N)
{
    __shared__ int lds[SCAN_BLOCK];
    const int b = blockIdx.x, t = threadIdx.x;
    const int idx0 = b * SCAN_TILE + t * SCAN_ITEMS;
    int vals[SCAN_ITEMS];
    int s = 0;
#pragma unroll
    for (int k = 0; k < SCAN_ITEMS; ++k) {
        const int idx = idx0 + k;
        const int c = (idx < N) ? count[idx] : 0;
        vals[k] = s; s += c;
    }
    lds[t] = s;
    __syncthreads();
    for (int off = 1; off < SCAN_BLOCK; off <<= 1) {
        const int xv = (t >= off) ? lds[t - off] : 0;
        __syncthreads();
        lds[t] += xv;
        __syncthreads();
    }
    const int excl = (t == 0) ? 0 : lds[t - 1];
#pragma unroll
    for (int k = 0; k < SCAN_ITEMS; ++k) {
        const int idx = idx0 + k;
        if (idx < N) base[idx] = excl + vals[k];
    }
    if (t == SCAN_BLOCK - 1) blocksums[b] = lds[t];
}

__global__ void scan_tops_kernel(int* __restrict__ blocksums, int nb)
{
    if (threadIdx.x == 0 && blockIdx.x == 0) {
        int s = 0;
        for (int i = 0; i < nb; ++i) { const int c = blocksums[i]; blocksums[i] = s; s += c; }
    }
}

__global__ __launch_bounds__(256) void scan_add_kernel(
    int* __restrict__ base, const int* __restrict__ blocksums, int N)
{
    const int i = blockIdx.x * 256 + threadIdx.x;
    if (i < N) base[i] += blocksums[i / SCAN_TILE];
}

// one THREAD per edge: scalar score + atomic-free CSR placement
__global__ __launch_bounds__(256) void edge_place_kernel(
    const int* __restrict__ edge, const int* __restrict__ etype,
    const float* __restrict__ G, int R,
    const float* __restrict__ su, const float* __restrict__ sv,
    const int* __restrict__ base, const int* __restrict__ rank,
    int4* __restrict__ csr, int E, int N)
{
    const int e = blockIdx.x * 256 + threadIdx.x;
    if (e >= E) return;
    const int s = edge[e];
    const int d = edge[(size_t)E + e];
    const int t = etype[e];
    if ((unsigned)s >= (unsigned)N || (unsigned)d >= (unsigned)N) return;

    const float g   = 0.5f * (G[s * R + t] + G[d * R + t]);
    const float raw = g * (su[s] + sv[d]);
    const float lr  = raw > 0.f ? raw : LRELU_ALPHA * raw;
    const float ee  = __expf(-lr);

    const int pos = base[s] + rank[e];
    csr[pos] = make_int4(d, __float_as_int(ee * g), __float_as_int(ee), 0);
}

// one WAVE per node: register accumulation, x8/x4-unrolled gather, fused finalize
__global__ __launch_bounds__(256) void aggregate_kernel(
    const int* __restrict__ base, const int4* __restrict__ csr,
    const float* __restrict__ u, const float* __restrict__ v,
    float* __restrict__ out, int N, int E)
{
    const int wave = threadIdx.x >> 6;
    const int lane = threadIdx.x & 63;
    const int n = blockIdx.x * 4 + wave;
    if (n >= N) return;

    const int rs = base[n];
    const int re = (n + 1 < N) ? base[n + 1] : E;

    float val = 0.f, sumw_p = 0.f, sumee_p = 0.f;

    for (int i = rs; i < re; i += 64) {
        const int m = min(64, re - i);
        int dl = 0; float wl = 0.f, eel = 0.f;
        if (lane < m) {
            const int4 p = csr[i + lane];
            dl  = p.x;
            wl  = __int_as_float(p.y);
            eel = __int_as_float(p.z);
        }
        sumw_p  += wl;
        sumee_p += eel;
        int j = 0;
        for (; j + 8 <= m; j += 8) {
            int   dd[8]; float ww[8], vv[8];
#pragma unroll
            for (int k = 0; k < 8; ++k) {
                dd[k] = __shfl(dl, j + k, 64);
                ww[k] = __shfl(wl, j + k, 64);
            }
#pragma unroll
            for (int k = 0; k < 8; ++k) vv[k] = v[dd[k] * 64 + lane];
#pragma unroll
            for (int k = 0; k < 8; ++k) val += ww[k] * vv[k];
        }
        for (; j + 4 <= m; j += 4) {
            int   dd[4]; float ww[4], vv[4];
#pragma unroll
            for (int k = 0; k < 4; ++k) {
                dd[k] = __shfl(dl, j + k, 64);
                ww[k] = __shfl(wl, j + k, 64);
            }
#pragma unroll
            for (int k = 0; k < 4; ++k) vv[k] = v[dd[k] * 64 + lane];
#pragma unroll
            for (int k = 0; k < 4; ++k) val += ww[k] * vv[k];
        }
        for (; j < m; ++j) {
            const int   dj = __shfl(dl, j, 64);
            const float wj = __shfl(wl, j, 64);
            val += wj * v[dj * 64 + lane];
        }
    }

    float sumw = sumw_p, sumee = sumee_p;
#pragma unroll
    for (int m2 = 1; m2 < 64; m2 <<= 1) {
        sumw  += __shfl_xor(sumw,  m2, 64);
        sumee += __shfl_xor(sumee, m2, 64);
    }

    val += sumw * u[n * 64 + lane];
    const float r = (sumee == 0.f) ? 1e-12f : sumee;
    const float h = val / r;
    out[n * 64 + lane] = (h > 0.f) ? h : expm1f(h);
}

extern "C" void kernel_launch(void* const* d_in, const int* in_sizes, int n_in,
                              void* d_out, int out_size, void* d_ws, size_t ws_size,
                              hipStream_t stream)
{
    const float* x     = (const float*)d_in[0];
    const int*   edge  = (const int*)d_in[1];
    // d_in[2] = edge_embed: unused by the reference computation
    const int*   etype = (const int*)d_in[3];
    const float* G     = (const float*)d_in[4];
    const float* a     = (const float*)d_in[5];
    const float* a2    = (const float*)d_in[6];

    const int N = in_sizes[0] / 64;
    const int E = in_sizes[1] / 2;
    const int R = in_sizes[4] / N;

    float* out = (float*)d_out;

    // workspace layout (~42 MB):
    // u[N*64] | v[N*64] | su[N] | sv[N] | count[N] | base[N] |
    // blocksums[nsb] | rank[E] | csr[E] (int4)
    float* u      = (float*)d_ws;
    float* v      = u + (size_t)N * 64;
    float* su     = v + (size_t)N * 64;
    float* sv     = su + N;
    int*   count  = (int*)(sv + N);
    int*   base   = count + N;
    const int nsb = (N + SCAN_TILE - 1) / SCAN_TILE;
    int*   blocksums = base + N;
    int*   rank   = blocksums + ((nsb + 63) & ~63);
    int*   tail   = rank + E;
    int4*  csr    = (int4*)((((uintptr_t)tail) + 15) & ~(uintptr_t)15);

    node_transform_kernel<<<dim3((N + 3) / 4), dim3(256), 0, stream>>>(
        x, a, a2, u, v, su, sv, count, N);
    hist_kernel<<<dim3((E + 255) / 256), dim3(256), 0, stream>>>(edge, count, rank, E);
    scan_blocks_kernel<<<dim3(nsb), dim3(SCAN_BLOCK), 0, stream>>>(count, base, blocksums, N);
    scan_tops_kernel<<<dim3(1), dim3(64), 0, stream>>>(blocksums, nsb);
    scan_add_kernel<<<dim3((N + 255) / 256), dim3(256), 0, stream>>>(base, blocksums, N);
    edge_place_kernel<<<dim3((E + 255) / 256), dim3(256), 0, stream>>>(
        edge, etype, G, R, su, sv, base, rank, csr, E, N);
    aggregate_kernel<<<dim3((N + 3) / 4), dim3(256), 0, stream>>>(
        base, csr, u, v, out, N, E);
}